// Round 5
// baseline (358.438 us; speedup 1.0000x reference)
//
#include <hip/hip_runtime.h>

#define EPSF 1e-6f

typedef _Float16 half8 __attribute__((ext_vector_type(8)));
typedef float f32x4 __attribute__((ext_vector_type(4)));

constexpr int B = 128, L = 512, S = 512, C = 64;
constexpr int TILE_R = 64;            // rows per pass-1 block
constexpr int TILES  = L / TILE_R;    // 8
constexpr int CHUNK  = 64;            // cols per k-chunk
constexpr int NCHUNK = S / CHUNK;     // 8
constexpr int HALVES = 2;             // S-split: each block does NCHUNK/HALVES chunks
constexpr int CPB    = NCHUNK / HALVES;   // 4 chunks per block

// workspace float offsets (row stats are per-half partials)
constexpr size_t WS_COLMAX = 0;
constexpr size_t WS_COLSUM = WS_COLMAX + (size_t)B * TILES * S;
constexpr size_t WS_COLSSQ = WS_COLSUM + (size_t)B * TILES * S;
constexpr size_t WS_COLP1  = WS_COLSSQ + (size_t)B * TILES * S;
constexpr size_t WS_ROWMAX = WS_COLP1  + (size_t)B * TILES * S;
constexpr size_t WS_ROWSUM = WS_ROWMAX + (size_t)B * L * HALVES;
constexpr size_t WS_ROWSSQ = WS_ROWSUM + (size_t)B * L * HALVES;
constexpr size_t WS_ROWP2  = WS_ROWSSQ + (size_t)B * L * HALVES;
constexpr size_t WS_NEGS   = WS_ROWP2  + (size_t)B * L * HALVES;
constexpr size_t WS_NEGC   = WS_NEGS   + (size_t)B * TILES * HALVES;
// frag-swizzled fp16 hi/lo planes: per (b,tile) 1024 half8 = 4096 floats
constexpr size_t WS_QF     = WS_NEGC   + (size_t)B * TILES * HALVES;
constexpr size_t WS_KF     = WS_QF     + (size_t)B * TILES * 4096;

constexpr int CONV_BLOCKS = B * (TILES + NCHUNK); // 2048 q/k convert jobs

__device__ inline void loadTile(const float* __restrict__ g, float4 v[4], int t)
{
    const float* src = g + (t >> 2) * 64 + (t & 3) * 16;
    v[0] = *(const float4*)(src);
    v[1] = *(const float4*)(src + 4);
    v[2] = *(const float4*)(src + 8);
    v[3] = *(const float4*)(src + 12);
}

// frag-swizzled hi/lo planes; lane-linear so pass1's global_load_lds (wave base
// + lane*16) reproduces the layout in LDS exactly.
__device__ inline void fragStore(const float4 v4[4], half8* dhi, half8* dlo, int t)
{
    const int row = t >> 2, c0 = (t & 3) * 16;
    const float v[16] = {v4[0].x, v4[0].y, v4[0].z, v4[0].w, v4[1].x, v4[1].y, v4[1].z, v4[1].w,
                         v4[2].x, v4[2].y, v4[2].z, v4[2].w, v4[3].x, v4[3].y, v4[3].z, v4[3].w};
#pragma unroll
    for (int o = 0; o < 2; ++o) {
        const int cb     = c0 + o * 8;
        const int idx    = (row >> 4) * 2 + (cb >> 5);
        const int lane_s = (((cb >> 3) & 3) << 4) + (row & 15);
        half8 h, l;
#pragma unroll
        for (int j = 0; j < 8; ++j) {
            float f = v[o * 8 + j];
            _Float16 hi = (_Float16)f;
            h[j] = hi;
            l[j] = (_Float16)(f - (float)hi);
        }
        dhi[idx * 64 + lane_s] = h;
        dlo[idx * 64 + lane_s] = l;
    }
}

// Pre-pass: q/k -> frag planes (labels are NOT packed here: R3 showed the
// 134 MB pack read costs more in convert than it saves in pass1). Also zeroes
// the scalar-loss slot (replaces the hipMemsetAsync dispatch).
__global__ __launch_bounds__(256)
void convert_kernel(const float* __restrict__ q, const float* __restrict__ kmat,
                    float* __restrict__ ws, float* __restrict__ out)
{
    const int bidx = blockIdx.x;
    const int tid  = threadIdx.x;
    if (bidx == 0 && tid == 0) out[(size_t)B * S] = 0.f;

    const int b    = bidx >> 4;          // 16 jobs per b: 8 q-tiles + 8 k-chunks
    const int t16  = bidx & 15;
    const bool isq = (t16 < TILES);
    const int tile = isq ? t16 : t16 - TILES;

    const float* src = isq ? (q    + ((size_t)b * L + (size_t)tile * TILE_R) * C)
                           : (kmat + ((size_t)b * S + (size_t)tile * CHUNK)  * C);
    half8* base = (half8*)(ws + (isq ? WS_QF : WS_KF)) + (size_t)(b * TILES + tile) * 1024;

    float4 v[4];
    loadTile(src, v, tid);
    fragStore(v, base, base + 512, tid);
}

// async 16B global -> LDS copy (DMA path; __syncthreads drains vmcnt so the
// per-chunk barrier doubles as the wait — the stage issued at iter start has
// the whole MFMA+epilogue as cover, so the drain cost is ~0)
__device__ inline void gl16(const void* g, void* l)
{
    __builtin_amdgcn_global_load_lds((const __attribute__((address_space(1))) void*)g,
                                     (__attribute__((address_space(3))) void*)l, 16, 0, 0);
}

// R4 POST-MORTEM / OCCUPANCY MODEL: VALUBusy is a per-CU (4-SIMD) aggregate ->
// true SIMD issue efficiency was ~10% at ~2.2 resident blocks/CU across R0-R4;
// pass1 is latency-bound purely for lack of resident waves. This version
// targets 4 blocks/CU (16 waves): LDS exactly 40 KB (kbuf 32K + 8K colring,
// nred folded into colring memory) and VGPR <= 64 (waves_per_eu(4,8) cap) via
// (a) labels as four 16-bit masks built in the prologue (4 VGPR, popcount for
// possum), (b) acc = 4 regs: per-ct fused MFMA->epilogue (also overlaps ct's
// MFMA with ct-1's VALU).
__global__ __launch_bounds__(256) __attribute__((amdgpu_waves_per_eu(4, 8)))
void pass1_kernel(const int* __restrict__ labels, float* __restrict__ ws)
{
    __shared__ half8 kbuf[2][1024];             // 32 KB double-buffered B frags
    __shared__ float4 colring[2][4][CHUNK];     // 8 KB per-wave column partial ring

    const int bidx = blockIdx.x;
    const int b    = bidx / (TILES * HALVES);
    const int rem  = bidx % (TILES * HALVES);
    const int tile = rem >> 1;
    const int half = rem & 1;
    const int chbase = half * CPB;
    const int tid  = threadIdx.x;
    const int lane = tid & 63;
    const int wave = tid >> 6;
    const int l15  = lane & 15;
    const int quad = lane >> 4;
    const int rowbase = tile * TILE_R;

    float* colmax_p = ws + WS_COLMAX;
    float* colsum_p = ws + WS_COLSUM;
    float* colssq_p = ws + WS_COLSSQ;
    float* colp1_p  = ws + WS_COLP1;
    float* rowmax_p = ws + WS_ROWMAX;
    float* rowsum_p = ws + WS_ROWSUM;
    float* rowssq_p = ws + WS_ROWSSQ;
    float* rowp2_p  = ws + WS_ROWP2;
    float* negs_p   = ws + WS_NEGS;
    float* negc_p   = ws + WS_NEGC;

    const int* lb = labels + ((size_t)b * L + rowbase) * S;

    const half8* qf  = (const half8*)(ws + WS_QF) + (size_t)(b * TILES + tile) * 1024;
    const half8* kf0 = (const half8*)(ws + WS_KF) + (size_t)b * NCHUNK * 1024;

    auto stage = [&](int ch, int bi) {
#pragma unroll
        for (int i = 0; i < 4; ++i)
            gl16(kf0 + (size_t)ch * 1024 + i * 256 + tid,
                 &kbuf[bi][i * 256 + (tid & 192)]);
    };

    stage(chbase, 0);   // chunk 0 DMA in flight while we do the prologue

    // A fragments: direct coalesced loads from the precomputed planes
    half8 ah0 = qf[(wave * 2 + 0) * 64 + lane];
    half8 ah1 = qf[(wave * 2 + 1) * 64 + lane];
    half8 al0 = qf[512 + (wave * 2 + 0) * 64 + lane];
    half8 al1 = qf[512 + (wave * 2 + 1) * 64 + lane];

    // labels: this thread's 64 elements folded to 4x16-bit masks (4 VGPR live;
    // bit ct*4+r of labm[cc] = label(row quad*4+r, col (chbase+cc)*64+ct*16+l15))
    unsigned labm[CPB];
#pragma unroll
    for (int cc = 0; cc < CPB; ++cc) {
        unsigned m = 0;
#pragma unroll
        for (int ct = 0; ct < 4; ++ct)
#pragma unroll
            for (int r = 0; r < 4; ++r) {
                int lab = __builtin_nontemporal_load(
                    &lb[(size_t)(wave * 16 + quad * 4 + r) * S
                        + (chbase + cc) * CHUNK + ct * 16 + l15]);
                m |= (unsigned)(lab == 1) << (ct * 4 + r);
            }
        labm[cc] = m;
    }

    float rmax[4], rsum[4], rssq[4], rp2[4];
#pragma unroll
    for (int i = 0; i < 4; ++i) { rmax[i] = -3.4e38f; rsum[i] = 0.f; rssq[i] = 0.f; rp2[i] = 0.f; }
    float negsum = 0.f;

    __syncthreads();   // drains vmcnt -> kbuf[0] ready

#pragma unroll
    for (int c4 = 0; c4 < CPB; ++c4) {
        const int ch = chbase + c4;
        if (c4 + 1 < CPB) stage(ch + 1, (c4 + 1) & 1);   // prefetch next chunk

        // deferred cross-wave combine of chunk c4-1 (ring slot (c4-1)&1 was
        // published by the barrier ending iter c4-1; that slot is next written
        // in iter c4+1, after this iter's barrier -> race-free)
        if (c4 > 0 && lane < 16) {
            const int col  = wave * 16 + l15;
            const int slot = (c4 - 1) & 1;
            float4 v = colring[slot][0][col];
            float m0 = v.x, s1 = v.y, s2 = v.z, pp = v.w;
#pragma unroll
            for (int w = 1; w < 4; ++w) {
                float4 u = colring[slot][w][col];
                m0 = fmaxf(m0, u.x); s1 += u.y; s2 += u.z; pp += u.w;
            }
            size_t idx = ((size_t)b * TILES + tile) * S + (size_t)(ch - 1) * CHUNK + col;
            colmax_p[idx] = m0; colsum_p[idx] = s1; colssq_p[idx] = s2; colp1_p[idx] = pp;
        }

        const half8* kb = kbuf[c4 & 1];
        const unsigned lm = labm[c4];    // static index (full unroll)

#pragma unroll
        for (int ct = 0; ct < 4; ++ct) {
            half8 bh0 = kb[(ct * 2 + 0) * 64 + lane];
            half8 bh1 = kb[(ct * 2 + 1) * 64 + lane];
            half8 bl0 = kb[512 + (ct * 2 + 0) * 64 + lane];
            half8 bl1 = kb[512 + (ct * 2 + 1) * 64 + lane];
            f32x4 a = {0.f, 0.f, 0.f, 0.f};
            a = __builtin_amdgcn_mfma_f32_16x16x32_f16(ah0, bh0, a, 0, 0, 0);
            a = __builtin_amdgcn_mfma_f32_16x16x32_f16(ah0, bl0, a, 0, 0, 0);
            a = __builtin_amdgcn_mfma_f32_16x16x32_f16(al0, bh0, a, 0, 0, 0);
            a = __builtin_amdgcn_mfma_f32_16x16x32_f16(ah1, bh1, a, 0, 0, 0);
            a = __builtin_amdgcn_mfma_f32_16x16x32_f16(ah1, bl1, a, 0, 0, 0);
            a = __builtin_amdgcn_mfma_f32_16x16x32_f16(al1, bh1, a, 0, 0, 0);

            // per-ct fused epilogue: C/D layout col = l15, row = quad*4 + r
            float cmax = -3.4e38f, csum = 0.f, cssq = 0.f, cp1 = 0.f;
#pragma unroll
            for (int r = 0; r < 4; ++r) {
                int lab = (int)((lm >> (ct * 4 + r)) & 1u);
                float sim = fmaf(0.5f, a[r], 0.5f);
                rmax[r] = fmaxf(rmax[r], sim);
                rsum[r] += sim;
                rssq[r] = fmaf(sim, sim, rssq[r]);
                cmax = fmaxf(cmax, sim);
                csum += sim;
                cssq = fmaf(sim, sim, cssq);
                float sc  = fminf(fmaxf(sim, EPSF), 1.f - EPSF);
                bool  isp = (lab == 1);
                float pos = isp ? 1.f : 0.f;
                float t   = isp ? sc : (1.f - sc);
                float nl  = -__logf(t);
                float pn  = pos * nl;
                rp2[r] += pn;
                cp1 += pn;
                negsum += nl - pn;
            }
#pragma unroll
            for (int m = 16; m <= 32; m <<= 1) {
                cmax = fmaxf(cmax, __shfl_xor(cmax, m, 64));
                csum += __shfl_xor(csum, m, 64);
                cssq += __shfl_xor(cssq, m, 64);
                cp1  += __shfl_xor(cp1,  m, 64);
            }
            if (lane < 16)
                colring[c4 & 1][wave][ct * 16 + l15] = make_float4(cmax, csum, cssq, cp1);
        }

        // one barrier per chunk: drains stage(c4+1) (full-iter cover) AND
        // publishes colring[c4&1] / protects kbuf reuse
        __syncthreads();
    }

    // last chunk's cross-wave combine
    if (lane < 16) {
        const int col  = wave * 16 + l15;
        const int slot = (CPB - 1) & 1;
        float4 v = colring[slot][0][col];
        float m0 = v.x, s1 = v.y, s2 = v.z, pp = v.w;
#pragma unroll
        for (int w = 1; w < 4; ++w) {
            float4 u = colring[slot][w][col];
            m0 = fmaxf(m0, u.x); s1 += u.y; s2 += u.z; pp += u.w;
        }
        size_t idx = ((size_t)b * TILES + tile) * S + (size_t)(chbase + CPB - 1) * CHUNK + col;
        colmax_p[idx] = m0; colsum_p[idx] = s1; colssq_p[idx] = s2; colp1_p[idx] = pp;
    }

    // row reduce across l15 (lanes sharing quad): xor 1,2,4,8 -> per-half partial
#pragma unroll
    for (int r = 0; r < 4; ++r) {
#pragma unroll
        for (int m = 1; m <= 8; m <<= 1) {
            rmax[r] = fmaxf(rmax[r], __shfl_xor(rmax[r], m, 64));
            rsum[r] += __shfl_xor(rsum[r], m, 64);
            rssq[r] += __shfl_xor(rssq[r], m, 64);
            rp2[r]  += __shfl_xor(rp2[r],  m, 64);
        }
    }
    if (l15 == 0) {
#pragma unroll
        for (int r = 0; r < 4; ++r) {
            size_t idx = ((size_t)b * L + rowbase + wave * 16 + quad * 4 + r) * HALVES + half;
            rowmax_p[idx] = rmax[r]; rowsum_p[idx] = rsum[r];
            rowssq_p[idx] = rssq[r]; rowp2_p[idx]  = rp2[r];
        }
    }

    // negatives: possum via popcount of the label masks; block reduce through
    // colring slot-0 memory (slot 1 reads above are disjoint)
    int possum = __popc(labm[0]) + __popc(labm[1]) + __popc(labm[2]) + __popc(labm[3]);
    float negcnt = (float)(16 * CPB - possum);
#pragma unroll
    for (int m = 1; m <= 32; m <<= 1) {
        negsum += __shfl_xor(negsum, m, 64);
        negcnt += __shfl_xor(negcnt, m, 64);
    }
    float* nscr = (float*)colring;   // reuse slot-0 bytes as scratch
    if (lane == 0) { nscr[wave * 2] = negsum; nscr[wave * 2 + 1] = negcnt; }
    __syncthreads();
    if (tid == 0) {
        float ns = 0.f, nc = 0.f;
        for (int w = 0; w < 4; ++w) { ns += nscr[w * 2]; nc += nscr[w * 2 + 1]; }
        negs_p[bidx] = ns; negc_p[bidx] = nc;
    }
}

template <bool MAX>
__device__ inline float bred(float v, float* red)
{
#pragma unroll
    for (int m = 1; m <= 32; m <<= 1) {
        float o = __shfl_xor(v, m, 64);
        v = MAX ? fmaxf(v, o) : (v + o);
    }
    const int wave = threadIdx.x >> 6;
    const int lane = threadIdx.x & 63;
    if (lane == 0) red[wave] = v;
    __syncthreads();
    if (threadIdx.x == 0) {
        float r = red[0];
        for (int w = 1; w < 8; ++w) r = MAX ? fmaxf(r, red[w]) : (r + red[w]);
        red[8] = r;
    }
    __syncthreads();
    float out = red[8];
    __syncthreads();   // protect red[] before next reduction reuses it
    return out;
}

// grid (B, 2): y==0 -> column path (sharp1 + loss1), y==1 -> row path (loss2 + loss3)
__global__ __launch_bounds__(512)
void pass2_kernel(const float* __restrict__ ws, float* __restrict__ out)
{
    __shared__ float red[9];
    const int b = blockIdx.x;
    const int s = threadIdx.x;

    if (blockIdx.y == 0) {
        const float* colmax_p = ws + WS_COLMAX;
        const float* colsum_p = ws + WS_COLSUM;
        const float* colssq_p = ws + WS_COLSSQ;
        const float* colp1_p  = ws + WS_COLP1;

        float m = -3.4e38f, sm = 0.f, sq = 0.f, p1 = 0.f;
#pragma unroll
        for (int t = 0; t < TILES; ++t) {
            size_t idx = ((size_t)b * TILES + t) * S + s;
            m = fmaxf(m, colmax_p[idx]);
            sm += colsum_p[idx];
            sq += colssq_p[idx];
            p1 += colp1_p[idx];
        }
        float mean  = sm * (1.f / L);
        float var   = (sq - sm * sm * (1.f / L)) * (1.f / (L - 1));
        float score = (m - mean) / sqrtf(var);

        float gmax = bred<true>(score, red);
        float e    = __expf(score - gmax);
        float esum = bred<false>(e, red);
        float sharp1 = e / esum;
        out[(size_t)b * S + s] = sharp1;
        float loss1 = bred<false>(sharp1 * p1, red);
        if (s == 0) atomicAdd(out + (size_t)B * S, loss1 * (0.5f / B));
    } else {
        const float* rowmax_p = ws + WS_ROWMAX;
        const float* rowsum_p = ws + WS_ROWSUM;
        const float* rowssq_p = ws + WS_ROWSSQ;
        const float* rowp2_p  = ws + WS_ROWP2;
        const float* negs_p   = ws + WS_NEGS;
        const float* negc_p   = ws + WS_NEGC;

        size_t ridx = ((size_t)b * L + s) * HALVES;
        float m2 = rowmax_p[ridx], sm2 = rowsum_p[ridx];
        float sq2 = rowssq_p[ridx], p2 = rowp2_p[ridx];
#pragma unroll
        for (int h = 1; h < HALVES; ++h) {
            m2 = fmaxf(m2, rowmax_p[ridx + h]);
            sm2 += rowsum_p[ridx + h];
            sq2 += rowssq_p[ridx + h];
            p2  += rowp2_p[ridx + h];
        }
        float mean2  = sm2 * (1.f / S);
        float var2   = (sq2 - sm2 * sm2 * (1.f / S)) * (1.f / (S - 1));
        float score2 = (m2 - mean2) / sqrtf(var2);

        float gmax2 = bred<true>(score2, red);
        float e2    = __expf(score2 - gmax2);
        float esum2 = bred<false>(e2, red);
        float loss2 = bred<false>((e2 / esum2) * p2, red);

        if (s == 0) {
            float ns = 0.f, nc = 0.f;
            for (int t = 0; t < TILES * HALVES; ++t) {
                ns += negs_p[b * TILES * HALVES + t];
                nc += negc_p[b * TILES * HALVES + t];
            }
            atomicAdd(out + (size_t)B * S, (0.5f * loss2 + ns / nc) * (1.f / B));
        }
    }
}

extern "C" void kernel_launch(void* const* d_in, const int* in_sizes, int n_in,
                              void* d_out, int out_size, void* d_ws, size_t ws_size,
                              hipStream_t stream)
{
    const float* q      = (const float*)d_in[0];
    const float* k      = (const float*)d_in[1];
    const int*   labels = (const int*)d_in[2];
    float* out = (float*)d_out;
    float* ws  = (float*)d_ws;

    convert_kernel<<<dim3(CONV_BLOCKS), dim3(256), 0, stream>>>(q, k, ws, out);
    pass1_kernel<<<dim3(B * TILES * HALVES), dim3(256), 0, stream>>>(labels, ws);
    pass2_kernel<<<dim3(B, 2), dim3(512), 0, stream>>>(ws, out);
}

// Round 6
// 316.942 us; speedup vs baseline: 1.1309x; 1.1309x over previous
//
#include <hip/hip_runtime.h>

#define EPSF 1e-6f
#define LN2F 0.69314718055994531f

typedef _Float16 half8 __attribute__((ext_vector_type(8)));
typedef float f32x4 __attribute__((ext_vector_type(4)));

constexpr int B = 128, L = 512, S = 512, C = 64;
constexpr int TILE_R = 64;            // rows per pass-1 block
constexpr int TILES  = L / TILE_R;    // 8
constexpr int CHUNK  = 64;            // cols per k-chunk
constexpr int NCHUNK = S / CHUNK;     // 8
constexpr int HALVES = 2;             // S-split: each block does NCHUNK/HALVES chunks
constexpr int CPB    = NCHUNK / HALVES;   // 4 chunks per block

// workspace float offsets (row stats are per-half partials)
constexpr size_t WS_COLMAX = 0;
constexpr size_t WS_COLSUM = WS_COLMAX + (size_t)B * TILES * S;
constexpr size_t WS_COLSSQ = WS_COLSUM + (size_t)B * TILES * S;
constexpr size_t WS_COLP1  = WS_COLSSQ + (size_t)B * TILES * S;
constexpr size_t WS_ROWMAX = WS_COLP1  + (size_t)B * TILES * S;
constexpr size_t WS_ROWSUM = WS_ROWMAX + (size_t)B * L * HALVES;
constexpr size_t WS_ROWSSQ = WS_ROWSUM + (size_t)B * L * HALVES;
constexpr size_t WS_ROWP2  = WS_ROWSSQ + (size_t)B * L * HALVES;
constexpr size_t WS_NEGS   = WS_ROWP2  + (size_t)B * L * HALVES;
constexpr size_t WS_NEGC   = WS_NEGS   + (size_t)B * TILES * HALVES;
// frag-swizzled fp16 hi/lo planes: per (b,tile) 1024 half8 = 4096 floats
constexpr size_t WS_QF     = WS_NEGC   + (size_t)B * TILES * HALVES;
constexpr size_t WS_KF     = WS_QF     + (size_t)B * TILES * 4096;

constexpr int CONV_BLOCKS = B * (TILES + NCHUNK); // 2048 q/k convert jobs

__device__ inline void loadTile(const float* __restrict__ g, float4 v[4], int t)
{
    const float* src = g + (t >> 2) * 64 + (t & 3) * 16;
    v[0] = *(const float4*)(src);
    v[1] = *(const float4*)(src + 4);
    v[2] = *(const float4*)(src + 8);
    v[3] = *(const float4*)(src + 12);
}

// frag-swizzled hi/lo planes; lane-linear so pass1's global_load_lds (wave base
// + lane*16) reproduces the layout in LDS exactly.
__device__ inline void fragStore(const float4 v4[4], half8* dhi, half8* dlo, int t)
{
    const int row = t >> 2, c0 = (t & 3) * 16;
    const float v[16] = {v4[0].x, v4[0].y, v4[0].z, v4[0].w, v4[1].x, v4[1].y, v4[1].z, v4[1].w,
                         v4[2].x, v4[2].y, v4[2].z, v4[2].w, v4[3].x, v4[3].y, v4[3].z, v4[3].w};
#pragma unroll
    for (int o = 0; o < 2; ++o) {
        const int cb     = c0 + o * 8;
        const int idx    = (row >> 4) * 2 + (cb >> 5);
        const int lane_s = (((cb >> 3) & 3) << 4) + (row & 15);
        half8 h, l;
#pragma unroll
        for (int j = 0; j < 8; ++j) {
            float f = v[o * 8 + j];
            _Float16 hi = (_Float16)f;
            h[j] = hi;
            l[j] = (_Float16)(f - (float)hi);
        }
        dhi[idx * 64 + lane_s] = h;
        dlo[idx * 64 + lane_s] = l;
    }
}

// Pre-pass: q/k -> frag planes; also zeroes the scalar-loss slot.
__global__ __launch_bounds__(256)
void convert_kernel(const float* __restrict__ q, const float* __restrict__ kmat,
                    float* __restrict__ ws, float* __restrict__ out)
{
    const int bidx = blockIdx.x;
    const int tid  = threadIdx.x;
    if (bidx == 0 && tid == 0) out[(size_t)B * S] = 0.f;

    const int b    = bidx >> 4;          // 16 jobs per b: 8 q-tiles + 8 k-chunks
    const int t16  = bidx & 15;
    const bool isq = (t16 < TILES);
    const int tile = isq ? t16 : t16 - TILES;

    const float* src = isq ? (q    + ((size_t)b * L + (size_t)tile * TILE_R) * C)
                           : (kmat + ((size_t)b * S + (size_t)tile * CHUNK)  * C);
    half8* base = (half8*)(ws + (isq ? WS_QF : WS_KF)) + (size_t)(b * TILES + tile) * 1024;

    float4 v[4];
    loadTile(src, v, tid);
    fragStore(v, base, base + 512, tid);
}

// async 16B global -> LDS copy (DMA path; __syncthreads drains vmcnt so the
// per-chunk barrier doubles as the wait — the stage issued at iter start has
// the whole MFMA+epilogue as cover)
__device__ inline void gl16(const void* g, void* l)
{
    __builtin_amdgcn_global_load_lds((const __attribute__((address_space(1))) void*)g,
                                     (__attribute__((address_space(3))) void*)l, 16, 0, 0);
}

// R5 POST-MORTEM: forcing VGPR<=64 via waves_per_eu(4,8) spilled (366 MB scratch
// writes). This version REDUCES DEMAND instead and lets occupancy follow:
//  - slim epilogue (~15 ops/elem vs ~21): log2-domain NLL scaled once at the
//    end; negsum derived from nlsum - sum(rp2); clamp on selected t only
//  - labels as 4x16-bit masks (4 VGPR vs 16), possum via popcount
//  - LDS exactly 40 KB (kbuf 32K + 8K colring 2-slot ring w/ deferred combine,
//    nred folded into ring bytes) -> LDS admits 4 blocks/CU
// waves_per_eu stays (3,8): no forced cap, no spill risk; if demand lands <=64
// we get 4 waves/SIMD for free.
__global__ __launch_bounds__(256) __attribute__((amdgpu_waves_per_eu(3, 8)))
void pass1_kernel(const int* __restrict__ labels, float* __restrict__ ws)
{
    __shared__ half8 kbuf[2][1024];             // 32 KB double-buffered B frags
    __shared__ float4 colring[2][4][CHUNK];     // 8 KB per-wave column partial ring

    const int bidx = blockIdx.x;
    const int b    = bidx / (TILES * HALVES);
    const int rem  = bidx % (TILES * HALVES);
    const int tile = rem >> 1;
    const int half = rem & 1;
    const int chbase = half * CPB;
    const int tid  = threadIdx.x;
    const int lane = tid & 63;
    const int wave = tid >> 6;
    const int l15  = lane & 15;
    const int quad = lane >> 4;
    const int rowbase = tile * TILE_R;

    float* colmax_p = ws + WS_COLMAX;
    float* colsum_p = ws + WS_COLSUM;
    float* colssq_p = ws + WS_COLSSQ;
    float* colp1_p  = ws + WS_COLP1;
    float* rowmax_p = ws + WS_ROWMAX;
    float* rowsum_p = ws + WS_ROWSUM;
    float* rowssq_p = ws + WS_ROWSSQ;
    float* rowp2_p  = ws + WS_ROWP2;
    float* negs_p   = ws + WS_NEGS;
    float* negc_p   = ws + WS_NEGC;

    const int* lb = labels + ((size_t)b * L + rowbase) * S;

    const half8* qf  = (const half8*)(ws + WS_QF) + (size_t)(b * TILES + tile) * 1024;
    const half8* kf0 = (const half8*)(ws + WS_KF) + (size_t)b * NCHUNK * 1024;

    auto stage = [&](int ch, int bi) {
#pragma unroll
        for (int i = 0; i < 4; ++i)
            gl16(kf0 + (size_t)ch * 1024 + i * 256 + tid,
                 &kbuf[bi][i * 256 + (tid & 192)]);
    };

    stage(chbase, 0);   // chunk 0 DMA in flight while we do the prologue

    // A fragments: direct coalesced loads from the precomputed planes
    half8 ah0 = qf[(wave * 2 + 0) * 64 + lane];
    half8 ah1 = qf[(wave * 2 + 1) * 64 + lane];
    half8 al0 = qf[512 + (wave * 2 + 0) * 64 + lane];
    half8 al1 = qf[512 + (wave * 2 + 1) * 64 + lane];

    // labels folded to 4x16-bit masks (bit ct*4+r of labm[cc] = label of
    // (row quad*4+r, col (chbase+cc)*64+ct*16+l15)); latency hidden by stage(0)
    unsigned labm[CPB];
#pragma unroll
    for (int cc = 0; cc < CPB; ++cc) {
        unsigned m = 0;
#pragma unroll
        for (int ct = 0; ct < 4; ++ct)
#pragma unroll
            for (int r = 0; r < 4; ++r) {
                int lab = __builtin_nontemporal_load(
                    &lb[(size_t)(wave * 16 + quad * 4 + r) * S
                        + (chbase + cc) * CHUNK + ct * 16 + l15]);
                m |= (unsigned)(lab == 1) << (ct * 4 + r);
            }
        labm[cc] = m;
    }

    float rmax[4], rsum[4], rssq[4], rp2[4];
#pragma unroll
    for (int i = 0; i < 4; ++i) { rmax[i] = -3.4e38f; rsum[i] = 0.f; rssq[i] = 0.f; rp2[i] = 0.f; }
    float nlsum = 0.f;   // sum of log2(t) over ALL elements (negative)

    __syncthreads();   // drains vmcnt -> kbuf[0] ready

#pragma unroll
    for (int c4 = 0; c4 < CPB; ++c4) {
        const int ch = chbase + c4;
        if (c4 + 1 < CPB) stage(ch + 1, (c4 + 1) & 1);   // prefetch next chunk

        // deferred cross-wave combine of chunk c4-1 (slot published by the
        // barrier ending iter c4-1; next rewritten in iter c4+1 -> race-free)
        if (c4 > 0 && lane < 16) {
            const int col  = wave * 16 + l15;
            const int slot = (c4 - 1) & 1;
            float4 v = colring[slot][0][col];
            float m0 = v.x, s1 = v.y, s2 = v.z, pp = v.w;
#pragma unroll
            for (int w = 1; w < 4; ++w) {
                float4 u = colring[slot][w][col];
                m0 = fmaxf(m0, u.x); s1 += u.y; s2 += u.z; pp += u.w;
            }
            size_t idx = ((size_t)b * TILES + tile) * S + (size_t)(ch - 1) * CHUNK + col;
            colmax_p[idx] = m0; colsum_p[idx] = s1; colssq_p[idx] = s2; colp1_p[idx] = pp;
        }

        const half8* kb = kbuf[c4 & 1];
        const unsigned lm = labm[c4];    // static index (loop fully unrolled)

        f32x4 acc[4];
#pragma unroll
        for (int ct = 0; ct < 4; ++ct) {
            half8 bh0 = kb[(ct * 2 + 0) * 64 + lane];
            half8 bh1 = kb[(ct * 2 + 1) * 64 + lane];
            half8 bl0 = kb[512 + (ct * 2 + 0) * 64 + lane];
            half8 bl1 = kb[512 + (ct * 2 + 1) * 64 + lane];
            f32x4 a = {0.f, 0.f, 0.f, 0.f};
            a = __builtin_amdgcn_mfma_f32_16x16x32_f16(ah0, bh0, a, 0, 0, 0);
            a = __builtin_amdgcn_mfma_f32_16x16x32_f16(ah0, bl0, a, 0, 0, 0);
            a = __builtin_amdgcn_mfma_f32_16x16x32_f16(al0, bh0, a, 0, 0, 0);
            a = __builtin_amdgcn_mfma_f32_16x16x32_f16(ah1, bh1, a, 0, 0, 0);
            a = __builtin_amdgcn_mfma_f32_16x16x32_f16(ah1, bl1, a, 0, 0, 0);
            a = __builtin_amdgcn_mfma_f32_16x16x32_f16(al1, bh1, a, 0, 0, 0);
            acc[ct] = a;
        }

        // slim epilogue: C/D layout col = l15, row = quad*4 + r  [m89-verified]
        // NLL in log2 domain; scaled by -ln2 once per accumulator at the end.
#pragma unroll
        for (int ct = 0; ct < 4; ++ct) {
            float cmax = -3.4e38f, csum = 0.f, cssq = 0.f, cp1 = 0.f;
#pragma unroll
            for (int r = 0; r < 4; ++r) {
                const int lab = (int)((lm >> (ct * 4 + r)) & 1u);
                float sim = fmaf(0.5f, acc[ct][r], 0.5f);
                rmax[r] = fmaxf(rmax[r], sim);
                rsum[r] += sim;
                rssq[r] = fmaf(sim, sim, rssq[r]);
                cmax = fmaxf(cmax, sim);
                csum += sim;
                cssq = fmaf(sim, sim, cssq);
                float tt = lab ? sim : (1.f - sim);
                tt = fminf(fmaxf(tt, EPSF), 1.f - EPSF);
                float l2 = __log2f(tt);          // negative
                float pv = lab ? l2 : 0.f;
                rp2[r] += pv;                    // log2-domain pos-NLL (negative)
                cp1   += pv;
                nlsum += l2;                     // all elements
            }
            cp1 *= -LN2F;                        // natural-log positive NLL
#pragma unroll
            for (int m = 16; m <= 32; m <<= 1) {
                cmax = fmaxf(cmax, __shfl_xor(cmax, m, 64));
                csum += __shfl_xor(csum, m, 64);
                cssq += __shfl_xor(cssq, m, 64);
                cp1  += __shfl_xor(cp1,  m, 64);
            }
            if (lane < 16)
                colring[c4 & 1][wave][ct * 16 + l15] = make_float4(cmax, csum, cssq, cp1);
        }

        // one barrier per chunk: drains stage(c4+1) AND publishes colring slot
        __syncthreads();
    }

    // last chunk's cross-wave combine
    if (lane < 16) {
        const int col  = wave * 16 + l15;
        const int slot = (CPB - 1) & 1;
        float4 v = colring[slot][0][col];
        float m0 = v.x, s1 = v.y, s2 = v.z, pp = v.w;
#pragma unroll
        for (int w = 1; w < 4; ++w) {
            float4 u = colring[slot][w][col];
            m0 = fmaxf(m0, u.x); s1 += u.y; s2 += u.z; pp += u.w;
        }
        size_t idx = ((size_t)b * TILES + tile) * S + (size_t)(chbase + CPB - 1) * CHUNK + col;
        colmax_p[idx] = m0; colsum_p[idx] = s1; colssq_p[idx] = s2; colp1_p[idx] = pp;
    }

    // scale pos-NLL accumulators to natural log; derive negsum from nlsum
#pragma unroll
    for (int r = 0; r < 4; ++r) rp2[r] *= -LN2F;
    float negsum = fmaf(-LN2F, nlsum, -(rp2[0] + rp2[1] + rp2[2] + rp2[3]));

    // row reduce across l15 (lanes sharing quad): xor 1,2,4,8 -> per-half partial
#pragma unroll
    for (int r = 0; r < 4; ++r) {
#pragma unroll
        for (int m = 1; m <= 8; m <<= 1) {
            rmax[r] = fmaxf(rmax[r], __shfl_xor(rmax[r], m, 64));
            rsum[r] += __shfl_xor(rsum[r], m, 64);
            rssq[r] += __shfl_xor(rssq[r], m, 64);
            rp2[r]  += __shfl_xor(rp2[r],  m, 64);
        }
    }
    if (l15 == 0) {
#pragma unroll
        for (int r = 0; r < 4; ++r) {
            size_t idx = ((size_t)b * L + rowbase + wave * 16 + quad * 4 + r) * HALVES + half;
            rowmax_p[idx] = rmax[r]; rowsum_p[idx] = rsum[r];
            rowssq_p[idx] = rssq[r]; rowp2_p[idx]  = rp2[r];
        }
    }

    // negatives: possum via popcount; block reduce through colring slot-0 bytes
    // (slot-1 reads above touch disjoint addresses)
    int possum = __popc(labm[0]) + __popc(labm[1]) + __popc(labm[2]) + __popc(labm[3]);
    float negcnt = (float)(16 * CPB - possum);
#pragma unroll
    for (int m = 1; m <= 32; m <<= 1) {
        negsum += __shfl_xor(negsum, m, 64);
        negcnt += __shfl_xor(negcnt, m, 64);
    }
    float* nscr = (float*)colring;   // reuse slot-0 bytes as scratch
    if (lane == 0) { nscr[wave * 2] = negsum; nscr[wave * 2 + 1] = negcnt; }
    __syncthreads();
    if (tid == 0) {
        float ns = 0.f, nc = 0.f;
        for (int w = 0; w < 4; ++w) { ns += nscr[w * 2]; nc += nscr[w * 2 + 1]; }
        negs_p[bidx] = ns; negc_p[bidx] = nc;
    }
}

template <bool MAX>
__device__ inline float bred(float v, float* red)
{
#pragma unroll
    for (int m = 1; m <= 32; m <<= 1) {
        float o = __shfl_xor(v, m, 64);
        v = MAX ? fmaxf(v, o) : (v + o);
    }
    const int wave = threadIdx.x >> 6;
    const int lane = threadIdx.x & 63;
    if (lane == 0) red[wave] = v;
    __syncthreads();
    if (threadIdx.x == 0) {
        float r = red[0];
        for (int w = 1; w < 8; ++w) r = MAX ? fmaxf(r, red[w]) : (r + red[w]);
        red[8] = r;
    }
    __syncthreads();
    float out = red[8];
    __syncthreads();   // protect red[] before next reduction reuses it
    return out;
}

// grid (B, 2): y==0 -> column path (sharp1 + loss1), y==1 -> row path (loss2 + loss3)
__global__ __launch_bounds__(512)
void pass2_kernel(const float* __restrict__ ws, float* __restrict__ out)
{
    __shared__ float red[9];
    const int b = blockIdx.x;
    const int s = threadIdx.x;

    if (blockIdx.y == 0) {
        const float* colmax_p = ws + WS_COLMAX;
        const float* colsum_p = ws + WS_COLSUM;
        const float* colssq_p = ws + WS_COLSSQ;
        const float* colp1_p  = ws + WS_COLP1;

        float m = -3.4e38f, sm = 0.f, sq = 0.f, p1 = 0.f;
#pragma unroll
        for (int t = 0; t < TILES; ++t) {
            size_t idx = ((size_t)b * TILES + t) * S + s;
            m = fmaxf(m, colmax_p[idx]);
            sm += colsum_p[idx];
            sq += colssq_p[idx];
            p1 += colp1_p[idx];
        }
        float mean  = sm * (1.f / L);
        float var   = (sq - sm * sm * (1.f / L)) * (1.f / (L - 1));
        float score = (m - mean) / sqrtf(var);

        float gmax = bred<true>(score, red);
        float e    = __expf(score - gmax);
        float esum = bred<false>(e, red);
        float sharp1 = e / esum;
        out[(size_t)b * S + s] = sharp1;
        float loss1 = bred<false>(sharp1 * p1, red);
        if (s == 0) atomicAdd(out + (size_t)B * S, loss1 * (0.5f / B));
    } else {
        const float* rowmax_p = ws + WS_ROWMAX;
        const float* rowsum_p = ws + WS_ROWSUM;
        const float* rowssq_p = ws + WS_ROWSSQ;
        const float* rowp2_p  = ws + WS_ROWP2;
        const float* negs_p   = ws + WS_NEGS;
        const float* negc_p   = ws + WS_NEGC;

        size_t ridx = ((size_t)b * L + s) * HALVES;
        float m2 = rowmax_p[ridx], sm2 = rowsum_p[ridx];
        float sq2 = rowssq_p[ridx], p2 = rowp2_p[ridx];
#pragma unroll
        for (int h = 1; h < HALVES; ++h) {
            m2 = fmaxf(m2, rowmax_p[ridx + h]);
            sm2 += rowsum_p[ridx + h];
            sq2 += rowssq_p[ridx + h];
            p2  += rowp2_p[ridx + h];
        }
        float mean2  = sm2 * (1.f / S);
        float var2   = (sq2 - sm2 * sm2 * (1.f / S)) * (1.f / (S - 1));
        float score2 = (m2 - mean2) / sqrtf(var2);

        float gmax2 = bred<true>(score2, red);
        float e2    = __expf(score2 - gmax2);
        float esum2 = bred<false>(e2, red);
        float loss2 = bred<false>((e2 / esum2) * p2, red);

        if (s == 0) {
            float ns = 0.f, nc = 0.f;
            for (int t = 0; t < TILES * HALVES; ++t) {
                ns += negs_p[b * TILES * HALVES + t];
                nc += negc_p[b * TILES * HALVES + t];
            }
            atomicAdd(out + (size_t)B * S, (0.5f * loss2 + ns / nc) * (1.f / B));
        }
    }
}

extern "C" void kernel_launch(void* const* d_in, const int* in_sizes, int n_in,
                              void* d_out, int out_size, void* d_ws, size_t ws_size,
                              hipStream_t stream)
{
    const float* q      = (const float*)d_in[0];
    const float* k      = (const float*)d_in[1];
    const int*   labels = (const int*)d_in[2];
    float* out = (float*)d_out;
    float* ws  = (float*)d_ws;

    convert_kernel<<<dim3(CONV_BLOCKS), dim3(256), 0, stream>>>(q, k, ws, out);
    pass1_kernel<<<dim3(B * TILES * HALVES), dim3(256), 0, stream>>>(labels, ws);
    pass2_kernel<<<dim3(B, 2), dim3(512), 0, stream>>>(ws, out);
}

// Round 7
// 236.541 us; speedup vs baseline: 1.5153x; 1.3399x over previous
//
#include <hip/hip_runtime.h>

#define EPSF 1e-6f
#define LN2F 0.69314718055994531f

typedef _Float16 half8 __attribute__((ext_vector_type(8)));
typedef float f32x4 __attribute__((ext_vector_type(4)));

constexpr int B = 128, L = 512, S = 512, C = 64;
constexpr int TILE_R = 64;            // rows per pass-1 block
constexpr int TILES  = L / TILE_R;    // 8
constexpr int CHUNK  = 64;            // cols per k-chunk
constexpr int NCHUNK = S / CHUNK;     // 8
constexpr int HALVES = 2;             // S-split: each block does NCHUNK/HALVES chunks
constexpr int CPB    = NCHUNK / HALVES;   // 4 chunks per block

// workspace float offsets (row stats are per-half partials)
constexpr size_t WS_COLMAX = 0;
constexpr size_t WS_COLSUM = WS_COLMAX + (size_t)B * TILES * S;
constexpr size_t WS_COLSSQ = WS_COLSUM + (size_t)B * TILES * S;
constexpr size_t WS_COLP1  = WS_COLSSQ + (size_t)B * TILES * S;
constexpr size_t WS_ROWMAX = WS_COLP1  + (size_t)B * TILES * S;
constexpr size_t WS_ROWSUM = WS_ROWMAX + (size_t)B * L * HALVES;
constexpr size_t WS_ROWSSQ = WS_ROWSUM + (size_t)B * L * HALVES;
constexpr size_t WS_ROWP2  = WS_ROWSSQ + (size_t)B * L * HALVES;
constexpr size_t WS_NEGS   = WS_ROWP2  + (size_t)B * L * HALVES;
constexpr size_t WS_NEGC   = WS_NEGS   + (size_t)B * TILES * HALVES;

// Load a thread's 16 consecutive floats of a 64x64 tile: row = t>>2, c0 = (t&3)*16.
__device__ inline void loadTile(const float* __restrict__ g, float4 v[4], int t)
{
    const float* src = g + (t >> 2) * 64 + (t & 3) * 16;
    v[0] = *(const float4*)(src);
    v[1] = *(const float4*)(src + 4);
    v[2] = *(const float4*)(src + 8);
    v[3] = *(const float4*)(src + 12);
}

// Write regs into frag-swizzled fp16 hi/lo LDS:
// arr[(row>>4)*2 + (c>>5)][(((c>>3)&3)<<4) + (row&15)][c&7] -> fragment read is
// one lane-linear ds_read_b128. No __restrict__ on LDS params (round-6 lesson).
__device__ inline void stageW(const float4 v4[4], half8 (*hiA)[64], half8 (*loA)[64], int t)
{
    const int row = t >> 2, c0 = (t & 3) * 16;
    const float v[16] = {v4[0].x, v4[0].y, v4[0].z, v4[0].w, v4[1].x, v4[1].y, v4[1].z, v4[1].w,
                         v4[2].x, v4[2].y, v4[2].z, v4[2].w, v4[3].x, v4[3].y, v4[3].z, v4[3].w};
#pragma unroll
    for (int o = 0; o < 2; ++o) {
        const int cb     = c0 + o * 8;
        const int idx    = (row >> 4) * 2 + (cb >> 5);
        const int lane_s = (((cb >> 3) & 3) << 4) + (row & 15);
        half8 h, l;
#pragma unroll
        for (int j = 0; j < 8; ++j) {
            float f = v[o * 8 + j];
            _Float16 hi = (_Float16)f;
            h[j] = hi;
            l[j] = (_Float16)(f - (float)hi);
        }
        hiA[idx][lane_s] = h;
        loA[idx][lane_s] = l;
    }
}

// R6 POST-MORTEM: both "reduce VGPR demand" restructurings (R5 masks+fused acc,
// R6 masks+deferred combine) pushed demand past the waves_per_eu(3,8) cap of 85
// and spilled (151-366 MB scratch). This is the EXACT R0 structure (VGPR 84,
// no spill, proven) with only pressure-neutral edits: (1) scalar-loss slot
// zeroed here (memset dispatch dropped), (2) log2-domain NLL with one -ln2
// scale per accumulator at the end + negsum derived per-thread (nlsum replaces
// negsum: register-neutral), (3) nontemporal label loads.
__global__ __launch_bounds__(256) __attribute__((amdgpu_waves_per_eu(3, 8)))
void pass1_kernel(const float* __restrict__ q, const float* __restrict__ kmat,
                  const int* __restrict__ labels, float* __restrict__ ws,
                  float* __restrict__ outp)
{
    __shared__ half8 khiF[8][64], kloF[8][64];   // 16 KB: frag-swizzled k (q in prologue)
    __shared__ float4 colred4[4][CHUNK];         // 4 KB (shuffle-reduced partials)
    __shared__ float nred[4][2];

    const int bidx = blockIdx.x;
    const int b    = bidx / (TILES * HALVES);
    const int rem  = bidx % (TILES * HALVES);
    const int tile = rem >> 1;
    const int half = rem & 1;
    const int chbase = half * CPB;
    const int tid  = threadIdx.x;
    const int lane = tid & 63;
    const int wave = tid >> 6;
    const int l15  = lane & 15;
    const int quad = lane >> 4;
    const int rowbase = tile * TILE_R;

    if (bidx == 0 && tid == 0) outp[(size_t)B * S] = 0.f;   // replaces memset dispatch

    float* colmax_p = ws + WS_COLMAX;
    float* colsum_p = ws + WS_COLSUM;
    float* colssq_p = ws + WS_COLSSQ;
    float* colp1_p  = ws + WS_COLP1;
    float* rowmax_p = ws + WS_ROWMAX;
    float* rowsum_p = ws + WS_ROWSUM;
    float* rowssq_p = ws + WS_ROWSSQ;
    float* rowp2_p  = ws + WS_ROWP2;
    float* negs_p   = ws + WS_NEGS;
    float* negc_p   = ws + WS_NEGC;

    const float* kb = kmat + (size_t)b * S * C;
    const int*   lb = labels + ((size_t)b * L + rowbase) * S;

    // --- prologue: q -> frag-swizzled LDS -> A fragments in registers ---
    float4 tv[4];
    loadTile(q + ((size_t)b * L + rowbase) * C, tv, tid);
    stageW(tv, khiF, kloF, tid);
    // labels for first chunk (consumed in first epilogue; reloaded after each)
    int labn[16];
#pragma unroll
    for (int ct = 0; ct < 4; ++ct)
#pragma unroll
        for (int r = 0; r < 4; ++r)
            labn[ct * 4 + r] = __builtin_nontemporal_load(
                &lb[(size_t)(wave * 16 + quad * 4 + r) * S
                    + chbase * CHUNK + ct * 16 + l15]);
    __syncthreads();   // publish q staging before fragment reads
    half8 ah0 = khiF[wave * 2 + 0][lane], ah1 = khiF[wave * 2 + 1][lane];
    half8 al0 = kloF[wave * 2 + 0][lane], al1 = kloF[wave * 2 + 1][lane];
    // prefetch first k chunk into registers (khiF not overwritten until after S1)
    loadTile(kb + (size_t)chbase * CHUNK * C, tv, tid);

    float rmax[4], rsum[4], rssq[4], rp2[4];
#pragma unroll
    for (int i = 0; i < 4; ++i) { rmax[i] = -3.4e38f; rsum[i] = 0.f; rssq[i] = 0.f; rp2[i] = 0.f; }
    float nlsum = 0.f;   // sum of log2(t) over ALL elements (negative)
    int   possum = 0;

    for (int c4 = 0; c4 < CPB; ++c4) {
        const int ch = chbase + c4;
        __syncthreads();   // S1: prev chunk's khiF frag reads + colred writes complete
        // combine + store column partials of previous chunk (reads colred4)
        if (c4 > 0 && tid < CHUNK) {
            float4 v = colred4[0][tid];
            float m0 = v.x, s1 = v.y, s2 = v.z, pp = v.w;
#pragma unroll
            for (int w = 1; w < 4; ++w) {
                float4 u = colred4[w][tid];
                m0 = fmaxf(m0, u.x); s1 += u.y; s2 += u.z; pp += u.w;
            }
            size_t idx = ((size_t)b * TILES + tile) * S + (ch - 1) * CHUNK + tid;
            colmax_p[idx] = m0; colsum_p[idx] = s1; colssq_p[idx] = s2; colp1_p[idx] = pp;
        }
        stageW(tv, khiF, kloF, tid);           // convert + write k(ch)
        if (c4 + 1 < CPB)
            loadTile(kb + (size_t)(ch + 1) * CHUNK * C, tv, tid);   // prefetch k(ch+1)
        __syncthreads();   // S2: k(ch) visible; colred4 reads done before re-write

        f32x4 acc[4];
#pragma unroll
        for (int ct = 0; ct < 4; ++ct) {
            half8 bh0 = khiF[ct * 2 + 0][lane], bh1 = khiF[ct * 2 + 1][lane];
            half8 bl0 = kloF[ct * 2 + 0][lane], bl1 = kloF[ct * 2 + 1][lane];
            f32x4 a = {0.f, 0.f, 0.f, 0.f};
            a = __builtin_amdgcn_mfma_f32_16x16x32_f16(ah0, bh0, a, 0, 0, 0);
            a = __builtin_amdgcn_mfma_f32_16x16x32_f16(ah0, bl0, a, 0, 0, 0);
            a = __builtin_amdgcn_mfma_f32_16x16x32_f16(al0, bh0, a, 0, 0, 0);
            a = __builtin_amdgcn_mfma_f32_16x16x32_f16(ah1, bh1, a, 0, 0, 0);
            a = __builtin_amdgcn_mfma_f32_16x16x32_f16(ah1, bl1, a, 0, 0, 0);
            a = __builtin_amdgcn_mfma_f32_16x16x32_f16(al1, bh1, a, 0, 0, 0);
            acc[ct] = a;
        }

        // epilogue: C/D layout col = l15, row = quad*4 + r  [m89-verified]
        // log2-domain NLL: accumulate raw log2, scale by -ln2 once at the end.
#pragma unroll
        for (int ct = 0; ct < 4; ++ct) {
            float cmax = -3.4e38f, csum = 0.f, cssq = 0.f, cp1 = 0.f;
#pragma unroll
            for (int r = 0; r < 4; ++r) {
                int lab = labn[ct * 4 + r];
                float sim = fmaf(0.5f, acc[ct][r], 0.5f);
                rmax[r] = fmaxf(rmax[r], sim);
                rsum[r] += sim;
                rssq[r] = fmaf(sim, sim, rssq[r]);
                cmax = fmaxf(cmax, sim);
                csum += sim;
                cssq = fmaf(sim, sim, cssq);
                bool  isp = (lab == 1);
                float tt  = isp ? sim : (1.f - sim);
                tt = fminf(fmaxf(tt, EPSF), 1.f - EPSF);
                float l2 = __log2f(tt);          // negative
                float pv = isp ? l2 : 0.f;
                rp2[r] += pv;                    // log2-domain pos-NLL
                cp1   += pv;
                nlsum += l2;                     // all elements
                possum += lab;
            }
            cp1 *= -LN2F;                        // natural-log positive NLL
            // column reduce across quads (lanes sharing l15): xor 16, 32
#pragma unroll
            for (int m = 16; m <= 32; m <<= 1) {
                cmax = fmaxf(cmax, __shfl_xor(cmax, m, 64));
                csum += __shfl_xor(csum, m, 64);
                cssq += __shfl_xor(cssq, m, 64);
                cp1  += __shfl_xor(cp1,  m, 64);
            }
            if (lane < 16)
                colred4[wave][ct * 16 + l15] = make_float4(cmax, csum, cssq, cp1);
        }

        // prefetch next chunk's labels AFTER consumption (cover: next S1/S2 +
        // staging + MFMA of chunk ch+1)
        if (c4 + 1 < CPB) {
#pragma unroll
            for (int ct = 0; ct < 4; ++ct)
#pragma unroll
                for (int r = 0; r < 4; ++r)
                    labn[ct * 4 + r] = __builtin_nontemporal_load(
                        &lb[(size_t)(wave * 16 + quad * 4 + r) * S
                            + (ch + 1) * CHUNK + ct * 16 + l15]);
        }
    }

    __syncthreads();
    if (tid < CHUNK) {   // last chunk's column partials
        float4 v = colred4[0][tid];
        float m0 = v.x, s1 = v.y, s2 = v.z, pp = v.w;
#pragma unroll
        for (int w = 1; w < 4; ++w) {
            float4 u = colred4[w][tid];
            m0 = fmaxf(m0, u.x); s1 += u.y; s2 += u.z; pp += u.w;
        }
        size_t idx = ((size_t)b * TILES + tile) * S + (chbase + CPB - 1) * CHUNK + tid;
        colmax_p[idx] = m0; colsum_p[idx] = s1; colssq_p[idx] = s2; colp1_p[idx] = pp;
    }

    // scale pos-NLL accumulators to natural log; derive this thread's negsum
    // BEFORE the row shuffles consume rp2
#pragma unroll
    for (int r = 0; r < 4; ++r) rp2[r] *= -LN2F;
    float negsum = fmaf(-LN2F, nlsum, -(rp2[0] + rp2[1] + rp2[2] + rp2[3]));

    // row reduce across l15 (lanes sharing quad): xor 1,2,4,8 -> per-half partial
#pragma unroll
    for (int r = 0; r < 4; ++r) {
#pragma unroll
        for (int m = 1; m <= 8; m <<= 1) {
            rmax[r] = fmaxf(rmax[r], __shfl_xor(rmax[r], m, 64));
            rsum[r] += __shfl_xor(rsum[r], m, 64);
            rssq[r] += __shfl_xor(rssq[r], m, 64);
            rp2[r]  += __shfl_xor(rp2[r],  m, 64);
        }
    }
    if (l15 == 0) {
#pragma unroll
        for (int r = 0; r < 4; ++r) {
            size_t idx = ((size_t)b * L + rowbase + wave * 16 + quad * 4 + r) * HALVES + half;
            rowmax_p[idx] = rmax[r]; rowsum_p[idx] = rsum[r];
            rowssq_p[idx] = rssq[r]; rowp2_p[idx]  = rp2[r];
        }
    }

    // negatives: full block reduce (negcnt = elements - possum)
    float negcnt = (float)(16 * CPB - possum);
#pragma unroll
    for (int m = 1; m <= 32; m <<= 1) {
        negsum += __shfl_xor(negsum, m, 64);
        negcnt += __shfl_xor(negcnt, m, 64);
    }
    if (lane == 0) { nred[wave][0] = negsum; nred[wave][1] = negcnt; }
    __syncthreads();
    if (tid == 0) {
        float ns = 0.f, nc = 0.f;
        for (int w = 0; w < 4; ++w) { ns += nred[w][0]; nc += nred[w][1]; }
        negs_p[bidx] = ns; negc_p[bidx] = nc;
    }
}

template <bool MAX>
__device__ inline float bred(float v, float* red)
{
#pragma unroll
    for (int m = 1; m <= 32; m <<= 1) {
        float o = __shfl_xor(v, m, 64);
        v = MAX ? fmaxf(v, o) : (v + o);
    }
    const int wave = threadIdx.x >> 6;
    const int lane = threadIdx.x & 63;
    if (lane == 0) red[wave] = v;
    __syncthreads();
    if (threadIdx.x == 0) {
        float r = red[0];
        for (int w = 1; w < 8; ++w) r = MAX ? fmaxf(r, red[w]) : (r + red[w]);
        red[8] = r;
    }
    __syncthreads();
    float out = red[8];
    __syncthreads();   // protect red[] before next reduction reuses it
    return out;
}

// grid (B, 2): y==0 -> column path (sharp1 + loss1), y==1 -> row path (loss2 + loss3)
__global__ __launch_bounds__(512)
void pass2_kernel(const float* __restrict__ ws, float* __restrict__ out)
{
    __shared__ float red[9];
    const int b = blockIdx.x;
    const int s = threadIdx.x;

    if (blockIdx.y == 0) {
        const float* colmax_p = ws + WS_COLMAX;
        const float* colsum_p = ws + WS_COLSUM;
        const float* colssq_p = ws + WS_COLSSQ;
        const float* colp1_p  = ws + WS_COLP1;

        float m = -3.4e38f, sm = 0.f, sq = 0.f, p1 = 0.f;
#pragma unroll
        for (int t = 0; t < TILES; ++t) {
            size_t idx = ((size_t)b * TILES + t) * S + s;
            m = fmaxf(m, colmax_p[idx]);
            sm += colsum_p[idx];
            sq += colssq_p[idx];
            p1 += colp1_p[idx];
        }
        float mean  = sm * (1.f / L);
        float var   = (sq - sm * sm * (1.f / L)) * (1.f / (L - 1));
        float score = (m - mean) / sqrtf(var);

        float gmax = bred<true>(score, red);
        float e    = __expf(score - gmax);
        float esum = bred<false>(e, red);
        float sharp1 = e / esum;
        out[(size_t)b * S + s] = sharp1;
        float loss1 = bred<false>(sharp1 * p1, red);
        if (s == 0) atomicAdd(out + (size_t)B * S, loss1 * (0.5f / B));
    } else {
        const float* rowmax_p = ws + WS_ROWMAX;
        const float* rowsum_p = ws + WS_ROWSUM;
        const float* rowssq_p = ws + WS_ROWSSQ;
        const float* rowp2_p  = ws + WS_ROWP2;
        const float* negs_p   = ws + WS_NEGS;
        const float* negc_p   = ws + WS_NEGC;

        size_t ridx = ((size_t)b * L + s) * HALVES;
        float m2 = rowmax_p[ridx], sm2 = rowsum_p[ridx];
        float sq2 = rowssq_p[ridx], p2 = rowp2_p[ridx];
#pragma unroll
        for (int h = 1; h < HALVES; ++h) {
            m2 = fmaxf(m2, rowmax_p[ridx + h]);
            sm2 += rowsum_p[ridx + h];
            sq2 += rowssq_p[ridx + h];
            p2  += rowp2_p[ridx + h];
        }
        float mean2  = sm2 * (1.f / S);
        float var2   = (sq2 - sm2 * sm2 * (1.f / S)) * (1.f / (S - 1));
        float score2 = (m2 - mean2) / sqrtf(var2);

        float gmax2 = bred<true>(score2, red);
        float e2    = __expf(score2 - gmax2);
        float esum2 = bred<false>(e2, red);
        float loss2 = bred<false>((e2 / esum2) * p2, red);

        if (s == 0) {
            float ns = 0.f, nc = 0.f;
            for (int t = 0; t < TILES * HALVES; ++t) {
                ns += negs_p[b * TILES * HALVES + t];
                nc += negc_p[b * TILES * HALVES + t];
            }
            atomicAdd(out + (size_t)B * S, (0.5f * loss2 + ns / nc) * (1.f / B));
        }
    }
}

extern "C" void kernel_launch(void* const* d_in, const int* in_sizes, int n_in,
                              void* d_out, int out_size, void* d_ws, size_t ws_size,
                              hipStream_t stream)
{
    const float* q      = (const float*)d_in[0];
    const float* k      = (const float*)d_in[1];
    const int*   labels = (const int*)d_in[2];
    float* out = (float*)d_out;
    float* ws  = (float*)d_ws;

    pass1_kernel<<<dim3(B * TILES * HALVES), dim3(256), 0, stream>>>(q, k, labels, ws, out);
    pass2_kernel<<<dim3(B, 2), dim3(512), 0, stream>>>(ws, out);
}